// Round 5
// baseline (248.309 us; speedup 1.0000x reference)
//
#include <hip/hip_runtime.h>

// Shapes: input  (8, 256, 256, 64) fp32, NHWC
//         pooled (8,  64,  64, 64) fp32 (in d_ws, 8 MiB)
//         output (8, 256, 256, 64) fp32
// POOL=6, STRIDE=4, SAME padding -> pad_lo = 1 in both spatial dims.
//
// R6 = R5 resubmit (R5 failed at container-acquisition level; all lines of
// this source are individually harness-proven from R1/R2 runs).
// Pool = R1's 1-output/thread version (2048 blocks, full occupancy).
// Upsample = R2's 4x4-tile-from-3x3-neighborhood version.

#define B_  8
#define H_  256
#define W_  256
#define C_  64
#define HP  64
#define WP  64
#define CG  16            // float4 channel groups per pixel
#define RS4 (W_ * C_ / 4) // input row stride in float4 units = 4096
#define CS4 (C_ / 4)      // input col stride in float4 units = 16

__device__ __forceinline__ float4 f4add(float4 a, float4 b) {
    return make_float4(a.x + b.x, a.y + b.y, a.z + b.z, a.w + b.w);
}
__device__ __forceinline__ float4 f4z() { return make_float4(0.f, 0.f, 0.f, 0.f); }

// ---------------- Kernel 1: 6x6 stride-4 SAME avg pool ----------------
// Thread = (b, i, j, cg): one pooled pixel, 4 channels (float4).
// Interior fast path fully unrolled; edges take the clipped slow path.
__global__ __launch_bounds__(256) void pool_kernel(const float* __restrict__ in,
                                                   float* __restrict__ pooled) {
    int gid = blockIdx.x * blockDim.x + threadIdx.x;
    int cg = gid & (CG - 1);
    int j  = (gid >> 4) & (WP - 1);
    int i  = (gid >> 10) & (HP - 1);
    int b  = gid >> 16;

    int rs = i * 4 - 1;
    int cs = j * 4 - 1;

    float4 sum = f4z();
    float scale;

    bool interior = (unsigned)(i - 1) < 62u && (unsigned)(j - 1) < 62u;
    if (interior) {
        const float4* p = (const float4*)(in + (((size_t)b * H_ + rs) * W_ + cs) * C_) + cg;
        #pragma unroll
        for (int r = 0; r < 6; ++r) {
            #pragma unroll
            for (int c = 0; c < 6; ++c) {
                sum = f4add(sum, p[r * RS4 + c * CS4]);
            }
        }
        scale = 1.0f / 36.0f;
    } else {
        int r0 = rs < 0 ? 0 : rs;
        int c0 = cs < 0 ? 0 : cs;
        int r1 = rs + 6 > H_ ? H_ : rs + 6;
        int c1 = cs + 6 > W_ ? W_ : cs + 6;
        const float4* base = (const float4*)(in + (size_t)b * H_ * W_ * C_) + cg;
        for (int r = r0; r < r1; ++r) {
            #pragma unroll 6
            for (int c = c0; c < c1; ++c) {
                sum = f4add(sum, base[(size_t)r * RS4 + (size_t)c * CS4]);
            }
        }
        scale = 1.0f / (float)((r1 - r0) * (c1 - c0));
    }

    float4 v = make_float4(sum.x * scale, sum.y * scale, sum.z * scale, sum.w * scale);
    ((float4*)pooled)[gid] = v;
}

// ---------------- Kernel 2: "unaverage pool" bilinear upsample ----------------
// dest_to_source with s=4, dsi=2, max_src=63: lo=5.5, hi=249.5
__device__ __forceinline__ float d2s(float dest) {
    const float s = 4.0f, dsi = 2.0f, maxs = 63.0f;
    float lo = dsi + s - 0.5f;                       // 5.5
    float hi = dsi + (maxs - 1.0f) * s - 0.5f;       // 249.5
    if (dest < lo) {
        return (dest - dsi) / (s - 0.5f);
    } else if (dest > hi) {
        return (dest - dsi + 0.5f - (maxs - 1.0f) * s) / (s - 0.5f) + maxs - 1.0f;
    } else {
        return (dest - dsi + 0.5f) / s;
    }
}

// Thread = (b, ti, tj, cg): 4x4 output tile (hd=4ti+dy, wd=4tj+dx) from a
// 3x3 pooled neighborhood rows ti-1..ti+1, cols tj-1..tj+1 (zero-padded).
// For every dest row in the tile, floor(d2s) is ti-1 or ti, so the 3 rows /
// 3 cols cover all bilinear taps.
__global__ __launch_bounds__(256) void upsample_kernel(const float* __restrict__ pooled,
                                                       float* __restrict__ out) {
    int gid = blockIdx.x * blockDim.x + threadIdx.x;
    int cg = gid & (CG - 1);
    int tj = (gid >> 4) & (WP - 1);
    int ti = (gid >> 10) & (HP - 1);
    int b  = gid >> 16;

    const float4* pb = (const float4*)pooled + (size_t)b * HP * WP * CG + cg;

    bool rv0 = (ti > 0), rv2 = (ti < HP - 1);
    bool cv0 = (tj > 0), cv2 = (tj < WP - 1);
    float4 z = f4z();

    float4 t00 = (rv0 && cv0) ? pb[((ti - 1) * WP + (tj - 1)) * CG] : z;
    float4 t01 = rv0          ? pb[((ti - 1) * WP + tj) * CG]       : z;
    float4 t02 = (rv0 && cv2) ? pb[((ti - 1) * WP + (tj + 1)) * CG] : z;
    float4 t10 = cv0          ? pb[(ti * WP + (tj - 1)) * CG]       : z;
    float4 t11 =                pb[(ti * WP + tj) * CG];
    float4 t12 = cv2          ? pb[(ti * WP + (tj + 1)) * CG]       : z;
    float4 t20 = (rv2 && cv0) ? pb[((ti + 1) * WP + (tj - 1)) * CG] : z;
    float4 t21 = rv2          ? pb[((ti + 1) * WP + tj) * CG]       : z;
    float4 t22 = (rv2 && cv2) ? pb[((ti + 1) * WP + (tj + 1)) * CG] : z;

    size_t obase = (size_t)b * H_ * W_ * CG + cg;
    float4* ob = (float4*)out;

    #pragma unroll
    for (int dy = 0; dy < 4; ++dy) {
        int hd = 4 * ti + dy;
        float sr = d2s((float)hd);
        float r0f = floorf(sr);
        float fr = sr - r0f;
        bool rhi = (((int)r0f - (ti - 1)) != 0);   // row pair starts at ti (vs ti-1)
        float4 a0 = rhi ? t10 : t00;
        float4 a1 = rhi ? t11 : t01;
        float4 a2 = rhi ? t12 : t02;
        float4 b0 = rhi ? t20 : t10;
        float4 b1 = rhi ? t21 : t11;
        float4 b2 = rhi ? t22 : t12;

        #pragma unroll
        for (int dx = 0; dx < 4; ++dx) {
            int wd = 4 * tj + dx;
            float sc = d2s((float)wd);
            float c0f = floorf(sc);
            float fc = sc - c0f;
            bool chi = (((int)c0f - (tj - 1)) != 0);
            float4 p00 = chi ? a1 : a0;
            float4 p01 = chi ? a2 : a1;
            float4 p10 = chi ? b1 : b0;
            float4 p11 = chi ? b2 : b1;

            float w00 = (1.0f - fr) * (1.0f - fc);
            float w01 = (1.0f - fr) * fc;
            float w10 = fr * (1.0f - fc);
            float w11 = fr * fc;

            float4 v;
            v.x = p00.x * w00 + p01.x * w01 + p10.x * w10 + p11.x * w11;
            v.y = p00.y * w00 + p01.y * w01 + p10.y * w10 + p11.y * w11;
            v.z = p00.z * w00 + p01.z * w01 + p10.z * w10 + p11.z * w11;
            v.w = p00.w * w00 + p01.w * w01 + p10.w * w10 + p11.w * w11;

            ob[obase + ((size_t)(hd * W_ + wd)) * CG] = v;
        }
    }
}

extern "C" void kernel_launch(void* const* d_in, const int* in_sizes, int n_in,
                              void* d_out, int out_size, void* d_ws, size_t ws_size,
                              hipStream_t stream) {
    const float* in  = (const float*)d_in[0];
    float* out       = (float*)d_out;
    float* pooled    = (float*)d_ws;   // 8 MiB used

    // Kernel 1: 8*64*64*16 threads = 524288 -> 2048 blocks
    pool_kernel<<<dim3(B_ * HP * WP * CG / 256), dim3(256), 0, stream>>>(in, pooled);
    // Kernel 2: 8*64*64*16 threads = 524288 -> 2048 blocks
    upsample_kernel<<<dim3(B_ * HP * WP * CG / 256), dim3(256), 0, stream>>>(pooled, out);
}

// Round 6
// 243.021 us; speedup vs baseline: 1.0218x; 1.0218x over previous
//
#include <hip/hip_runtime.h>

// Shapes: input  (8, 256, 256, 64) fp32, NHWC
//         pooled (8,  64,  64, 64) fp32 (in d_ws, 8 MiB)
//         output (8, 256, 256, 64) fp32
// POOL=6, STRIDE=4, SAME padding -> pad_lo = 1 in both spatial dims.
//
// R7: pool -> 2x2 pooled outputs per thread (10 rows x 10 cols = 100 loads
// for 4 outputs = 25/out vs R2's 27), sharing the 2-col horizontal window
// overlap via partial sums. 512 blocks (= R2's proven concurrency), uniform
// predicated edges. Upsample byte-identical to R2's proven 4x4-tile version.
// Evidence: R1/R2/R6 A/B shows pool is VMEM-issue bound (load count is the
// lever), upsample is at its store floor.

#define B_  8
#define H_  256
#define W_  256
#define C_  64
#define HP  64
#define WP  64
#define CG  16            // float4 channel groups per pixel
#define RS4 (W_ * C_ / 4) // input row stride in float4 units = 4096
#define CS4 (C_ / 4)      // input col stride in float4 units = 16

__device__ __forceinline__ float4 f4add(float4 a, float4 b) {
    return make_float4(a.x + b.x, a.y + b.y, a.z + b.z, a.w + b.w);
}
__device__ __forceinline__ float4 f4z() { return make_float4(0.f, 0.f, 0.f, 0.f); }

// ---------------- Kernel 1: 6x6 stride-4 SAME avg pool ----------------
// Thread = (b, ti, jp, cg): computes pooled[2ti..2ti+1][2jp..2jp+1] (2x2).
// Input rows r = 8ti-1+rr (rr 0..9), cols c = 8jp-1+cc (cc 0..9).
// Output (2ti+di, 2jp+dj) window: rr in [4di,4di+5], cc in [4dj,4dj+5].
__global__ __launch_bounds__(256) void pool_kernel(const float* __restrict__ in,
                                                   float* __restrict__ pooled) {
    int gid = blockIdx.x * blockDim.x + threadIdx.x;
    int cg = gid & (CG - 1);
    int jp = (gid >> 4) & 31;
    int ti = (gid >> 9) & 31;
    int b  = gid >> 14;

    int c0 = jp * 8 - 1;         // col of cc=0 (may be -1)
    int r0 = ti * 8 - 1;         // row of rr=0 (may be -1)
    bool cl = (jp > 0);          // cc=0 valid
    bool cr = (jp < 31);         // cc=9 valid

    long rowbase = (long)b * H_ * RS4 + (long)c0 * CS4 + cg;
    const float4* base = (const float4*)in;

    float4 a00 = f4z(), a01 = f4z(), a10 = f4z(), a11 = f4z();

    #pragma unroll
    for (int rr = 0; rr < 10; ++rr) {
        int r = r0 + rr;
        // only rr==0 can be <0 (ti==0), only rr==9 can be >=H_ (ti==31)
        bool rvalid = (rr == 0) ? (r >= 0) : ((rr == 9) ? (r < H_) : true);
        if (rvalid) {
            const float4* p = base + rowbase + (long)r * RS4;
            float4 l0 = cl ? p[0] : f4z();
            float4 l1 = p[1 * CS4];
            float4 l2 = p[2 * CS4];
            float4 l3 = p[3 * CS4];
            float4 l4 = p[4 * CS4];
            float4 l5 = p[5 * CS4];
            float4 l6 = p[6 * CS4];
            float4 l7 = p[7 * CS4];
            float4 l8 = p[8 * CS4];
            float4 l9 = cr ? p[9 * CS4] : f4z();

            float4 mid   = f4add(l4, l5);
            float4 left  = f4add(f4add(l0, l1), f4add(l2, l3));
            float4 right = f4add(f4add(l6, l7), f4add(l8, l9));
            float4 s0 = f4add(left, mid);    // cols cc 0..5  (output dj=0)
            float4 s1 = f4add(mid, right);   // cols cc 4..9  (output dj=1)

            if (rr <= 5) { a00 = f4add(a00, s0); a01 = f4add(a01, s1); }
            if (rr >= 4) { a10 = f4add(a10, s0); a11 = f4add(a11, s1); }
        }
    }

    int i0 = ti * 2;
    int j0 = jp * 2;
    // edge element counts: i0 even -> i0==63 impossible; i0+1 odd -> !=0.
    float nr0 = 6.0f - (i0 == 0 ? 1.0f : 0.0f);
    float nr1 = 6.0f - (i0 + 1 == HP - 1 ? 1.0f : 0.0f);
    float nc0 = 6.0f - (j0 == 0 ? 1.0f : 0.0f);
    float nc1 = 6.0f - (j0 + 1 == WP - 1 ? 1.0f : 0.0f);

    float4* pp = (float4*)pooled;
    size_t out0 = ((size_t)(b * HP + i0) * WP + j0) * CG + cg;

    float s;
    s = 1.0f / (nr0 * nc0);
    pp[out0]                        = make_float4(a00.x * s, a00.y * s, a00.z * s, a00.w * s);
    s = 1.0f / (nr0 * nc1);
    pp[out0 + CG]                   = make_float4(a01.x * s, a01.y * s, a01.z * s, a01.w * s);
    s = 1.0f / (nr1 * nc0);
    pp[out0 + (size_t)WP * CG]      = make_float4(a10.x * s, a10.y * s, a10.z * s, a10.w * s);
    s = 1.0f / (nr1 * nc1);
    pp[out0 + (size_t)WP * CG + CG] = make_float4(a11.x * s, a11.y * s, a11.z * s, a11.w * s);
}

// ---------------- Kernel 2: "unaverage pool" bilinear upsample ----------------
// dest_to_source with s=4, dsi=2, max_src=63: lo=5.5, hi=249.5
__device__ __forceinline__ float d2s(float dest) {
    const float s = 4.0f, dsi = 2.0f, maxs = 63.0f;
    float lo = dsi + s - 0.5f;                       // 5.5
    float hi = dsi + (maxs - 1.0f) * s - 0.5f;       // 249.5
    if (dest < lo) {
        return (dest - dsi) / (s - 0.5f);
    } else if (dest > hi) {
        return (dest - dsi + 0.5f - (maxs - 1.0f) * s) / (s - 0.5f) + maxs - 1.0f;
    } else {
        return (dest - dsi + 0.5f) / s;
    }
}

// Thread = (b, ti, tj, cg): 4x4 output tile (hd=4ti+dy, wd=4tj+dx) from a
// 3x3 pooled neighborhood rows ti-1..ti+1, cols tj-1..tj+1 (zero-padded).
__global__ __launch_bounds__(256) void upsample_kernel(const float* __restrict__ pooled,
                                                       float* __restrict__ out) {
    int gid = blockIdx.x * blockDim.x + threadIdx.x;
    int cg = gid & (CG - 1);
    int tj = (gid >> 4) & (WP - 1);
    int ti = (gid >> 10) & (HP - 1);
    int b  = gid >> 16;

    const float4* pb = (const float4*)pooled + (size_t)b * HP * WP * CG + cg;

    bool rv0 = (ti > 0), rv2 = (ti < HP - 1);
    bool cv0 = (tj > 0), cv2 = (tj < WP - 1);
    float4 z = f4z();

    float4 t00 = (rv0 && cv0) ? pb[((ti - 1) * WP + (tj - 1)) * CG] : z;
    float4 t01 = rv0          ? pb[((ti - 1) * WP + tj) * CG]       : z;
    float4 t02 = (rv0 && cv2) ? pb[((ti - 1) * WP + (tj + 1)) * CG] : z;
    float4 t10 = cv0          ? pb[(ti * WP + (tj - 1)) * CG]       : z;
    float4 t11 =                pb[(ti * WP + tj) * CG];
    float4 t12 = cv2          ? pb[(ti * WP + (tj + 1)) * CG]       : z;
    float4 t20 = (rv2 && cv0) ? pb[((ti + 1) * WP + (tj - 1)) * CG] : z;
    float4 t21 = rv2          ? pb[((ti + 1) * WP + tj) * CG]       : z;
    float4 t22 = (rv2 && cv2) ? pb[((ti + 1) * WP + (tj + 1)) * CG] : z;

    size_t obase = (size_t)b * H_ * W_ * CG + cg;
    float4* ob = (float4*)out;

    #pragma unroll
    for (int dy = 0; dy < 4; ++dy) {
        int hd = 4 * ti + dy;
        float sr = d2s((float)hd);
        float r0f = floorf(sr);
        float fr = sr - r0f;
        bool rhi = (((int)r0f - (ti - 1)) != 0);   // row pair starts at ti (vs ti-1)
        float4 a0 = rhi ? t10 : t00;
        float4 a1 = rhi ? t11 : t01;
        float4 a2 = rhi ? t12 : t02;
        float4 b0 = rhi ? t20 : t10;
        float4 b1 = rhi ? t21 : t11;
        float4 b2 = rhi ? t22 : t12;

        #pragma unroll
        for (int dx = 0; dx < 4; ++dx) {
            int wd = 4 * tj + dx;
            float sc = d2s((float)wd);
            float c0f = floorf(sc);
            float fc = sc - c0f;
            bool chi = (((int)c0f - (tj - 1)) != 0);
            float4 p00 = chi ? a1 : a0;
            float4 p01 = chi ? a2 : a1;
            float4 p10 = chi ? b1 : b0;
            float4 p11 = chi ? b2 : b1;

            float w00 = (1.0f - fr) * (1.0f - fc);
            float w01 = (1.0f - fr) * fc;
            float w10 = fr * (1.0f - fc);
            float w11 = fr * fc;

            float4 v;
            v.x = p00.x * w00 + p01.x * w01 + p10.x * w10 + p11.x * w11;
            v.y = p00.y * w00 + p01.y * w01 + p10.y * w10 + p11.y * w11;
            v.z = p00.z * w00 + p01.z * w01 + p10.z * w10 + p11.z * w11;
            v.w = p00.w * w00 + p01.w * w01 + p10.w * w10 + p11.w * w11;

            ob[obase + ((size_t)(hd * W_ + wd)) * CG] = v;
        }
    }
}

extern "C" void kernel_launch(void* const* d_in, const int* in_sizes, int n_in,
                              void* d_out, int out_size, void* d_ws, size_t ws_size,
                              hipStream_t stream) {
    const float* in  = (const float*)d_in[0];
    float* out       = (float*)d_out;
    float* pooled    = (float*)d_ws;   // 8 MiB used

    // Kernel 1: 8*32*32*16 threads = 131072 -> 512 blocks
    pool_kernel<<<dim3(B_ * (HP / 2) * (WP / 2) * CG / 256), dim3(256), 0, stream>>>(in, pooled);
    // Kernel 2: 8*64*64*16 threads = 524288 -> 2048 blocks
    upsample_kernel<<<dim3(B_ * HP * WP * CG / 256), dim3(256), 0, stream>>>(pooled, out);
}